// Round 9
// baseline (1399.721 us; speedup 1.0000x reference)
//
#include <hip/hip_runtime.h>
#include <math.h>

#define N_NODES 100000
#define N_EDGES 3200000
#define F_IN    37
#define H_DIM   16
#define C_DIM   2

#define BUCKET_BITS 7
#define BUCKET_SZ   128
#define NBUCK       782          // ceil(100000/128)
#define CAP         4736         // bucket capacity: mean ~4092 + 10 sigma
#define NPBLK       512          // grid: 2 blocks/CU, all co-resident (see barrier)
#define NTHR        1024
#define EB          6250         // edges per P0 block (512*6250 = 3.2M exactly)
#define EPT_P       7            // ceil(6250/1024)
#define EPT_S       5            // ceil(CAP/1024)
#define NPAGE       782          // ceil(EB/8) pages for sweep lookup
#define EBUF_SLOTS  (NBUCK * CAP + EB)

// LDS layout: one flat block, phase-aliased.
#define SMEM_A      50048        // region A: P0 stage (50000) / P1 stage/xs
#define SMEM_TOTAL  61072        // + aux region (max 11012 for P0)

__device__ __forceinline__ unsigned bf16rne(float f) {
    unsigned u = __float_as_uint(f);
    return (u + 0x7FFFu + ((u >> 16) & 1u)) >> 16;
}
__device__ __forceinline__ int2 ldnt_i2(const int2* p) {
    long long v = __builtin_nontemporal_load((const long long*)p);
    return *(int2*)&v;
}
#define BLO(u) __uint_as_float((u) << 16)
#define BHI(u) __uint_as_float((u) & 0xFFFF0000u)
// compact edge decode: u = (w_bf16 << 17) | row   (w in [0,1) => sign bit 0)
#define EW(u)  __uint_as_float(((u) >> 17) << 16)
#define ER(u)  ((u) & 0x1FFFFu)

// Software grid barrier (graph-capture-safe; coop launch no-ops under capture,
// proven R8: absmax 0.859 == max|ref| vs zeroed out => kernel never ran).
// Safe: 2 blocks/CU x 256 CU = all 512 blocks resident (LDS 61KB<=80, <=64 VGPR
// via launch_bounds, 32 waves/CU). Device-scope fences cover XCD L2s (G16).
__device__ __forceinline__ void gridbar(int* bar, int idx) {
    __syncthreads();
    __threadfence();                           // release: flush this block's writes
    if (threadIdx.x == 0) {
        __hip_atomic_fetch_add(&bar[idx], 1, __ATOMIC_RELEASE,
                               __HIP_MEMORY_SCOPE_AGENT);
        while (__hip_atomic_load(&bar[idx], __ATOMIC_ACQUIRE,
                                 __HIP_MEMORY_SCOPE_AGENT) < NPBLK)
            __builtin_amdgcn_s_sleep(2);
    }
    __syncthreads();
    __threadfence();                           // acquire: drop stale cache lines
}

__global__ __launch_bounds__(NTHR, 8) void k_fused(
    const int* __restrict__ row, const int* __restrict__ col,
    const float* __restrict__ w, int* __restrict__ gcur, int* __restrict__ bar,
    int2* __restrict__ ebuf, const float* __restrict__ x,
    const float* __restrict__ W1, unsigned* __restrict__ ebuf4,
    int2* __restrict__ rp, float* __restrict__ dinv,
    unsigned* __restrict__ h1b, float* __restrict__ h2s,
    const float* __restrict__ b1, const float* __restrict__ W2,
    const float* __restrict__ b2, float* __restrict__ out)
{
    __shared__ __align__(16) char smem[SMEM_TOTAL];
    int t = threadIdx.x;

    // ================= P0: partition (LDS-staged counting sort -> linear out) =
    {
        int*  cnt   = (int*)(smem + SMEM_A);           // 782
        int*  base  = cnt + NBUCK;                     // 782
        int*  gbase = base + NBUCK;                    // 782
        int*  wscan = gbase + NBUCK;                   // 16
        unsigned short* pg2b = (unsigned short*)(wscan + 16); // 782
        int2* stage = (int2*)smem;                     // EB

        size_t e0 = (size_t)blockIdx.x * EB;
        int bk[EPT_P], lofs[EPT_P];

        if (t < NBUCK) cnt[t] = 0;
        __syncthreads();
        // pass A: count (keeps register liveness low across the scan)
#pragma unroll
        for (int k = 0; k < EPT_P; k++) {
            int i = k * NTHR + t;
            if (i < EB) {
                int c = __builtin_nontemporal_load(&col[e0 + i]);
                int b = (c >> BUCKET_BITS) & 1023;
                if (b >= NBUCK) b = NBUCK - 1;         // unreachable guard
                bk[k] = b;
                lofs[k] = atomicAdd(&cnt[b], 1);
            } else bk[k] = -1;
        }
        __syncthreads();
        // inclusive scan of cnt[782]: per-wave shfl + cross-wave
        {
            int lane = t & 63, wid = t >> 6;
            int v = (t < NBUCK) ? cnt[t] : 0;
#pragma unroll
            for (int d = 1; d < 64; d <<= 1) {
                int u = __shfl_up(v, d);
                if (lane >= d) v += u;
            }
            if (lane == 63) wscan[wid] = v;
            __syncthreads();
            if (wid == 0) {
                int u = (lane < 16) ? wscan[lane] : 0;
#pragma unroll
                for (int d = 1; d < 16; d <<= 1) {
                    int u2 = __shfl_up(u, d);
                    if (lane >= d) u += u2;
                }
                if (lane < 16) wscan[lane] = u;
            }
            __syncthreads();
            if (t < NBUCK) base[t] = v + ((wid > 0) ? wscan[wid - 1] : 0);
        }
        __syncthreads();
        // pass B: reload row/col/w (L3-warm), scatter into LDS bucket-sorted
#pragma unroll
        for (int k = 0; k < EPT_P; k++) {
            if (bk[k] >= 0) {
                int i = k * NTHR + t;
                int r = __builtin_nontemporal_load(&row[e0 + i]);
                int c = __builtin_nontemporal_load(&col[e0 + i]);
                float wv = __builtin_nontemporal_load(&w[e0 + i]);
                int pos = base[bk[k]] - cnt[bk[k]] + lofs[k];
                if (pos >= 0 && pos < EB)              // unreachable guard
                    stage[pos] = make_int2(
                        (r & 0x1FFFF) | ((c & (BUCKET_SZ - 1)) << 17),
                        __float_as_int(wv));
            }
        }
        if (t < NBUCK) {
            int st = base[t] - cnt[t], en = base[t];
            int p0 = (st + 7) >> 3, p1 = (en - 1) >> 3;
            if (p0 < 0) p0 = 0;
            if (p1 >= NPAGE) p1 = NPAGE - 1;           // unreachable guard
            for (int p = p0; p <= p1; p++) pg2b[p] = (unsigned short)t;
            gbase[t] = t * CAP + atomicAdd(&gcur[t], cnt[t]);
        }
        __syncthreads();
        for (int s2 = t; s2 < EB; s2 += NTHR) {
            int lo = pg2b[s2 >> 3];
            while (lo < NBUCK - 1 && base[lo] <= s2) lo++;
            int dst = gbase[lo] + (s2 - (base[lo] - cnt[lo]));
            if (dst >= 0 && dst < EBUF_SLOTS)          // unreachable guard
                ebuf[dst] = stage[s2];
        }
    }
    gridbar(bar, 0);

    // ================= P1: per-bucket sort -> ebuf4 + rp + dinv + h1b =========
    {
        int*   cnt1  = (int*)(smem + SMEM_A);          // 128
        int*   base1 = cnt1 + BUCKET_SZ;               // 128
        float* sdinv = (float*)(base1 + BUCKET_SZ);    // 128
        int*   wscan = (int*)(sdinv + BUCKET_SZ);      // 16
        float* sW    = (float*)(wscan + 16);           // 592
        int2*  stage = (int2*)smem;                    // CAP
        float* xs    = (float*)smem;                   // aliased after sort use

        for (int idx = t; idx < F_IN * H_DIM; idx += NTHR) sW[idx] = W1[idx];

        for (int b = blockIdx.x; b < NBUCK; b += NPBLK) {
            int s = b * CAP;
            int len = gcur[b];
            if (len > CAP) len = CAP;                  // unreachable guard
            int nbase = b << BUCKET_BITS;
            __syncthreads();                           // xs/stage free, sW ready
            if (t < BUCKET_SZ) cnt1[t] = 0;
            __syncthreads();

            int2 ed[EPT_S]; int cl[EPT_S], lofs[EPT_S];
#pragma unroll
            for (int k = 0; k < EPT_S; k++) {
                int i = k * NTHR + t;
                if (i < len) {
                    int2 v = *(const int2*)&ebuf[s + i];
                    ed[k] = v;
                    cl[k] = (v.x >> 17) & (BUCKET_SZ - 1);
                    lofs[k] = atomicAdd(&cnt1[cl[k]], 1);
                } else cl[k] = -1;
            }
            __syncthreads();
            // scan of cnt1[128]
            {
                int lane = t & 63, wid = t >> 6;
                int v = (t < BUCKET_SZ) ? cnt1[t] : 0;
#pragma unroll
                for (int d = 1; d < 64; d <<= 1) {
                    int u = __shfl_up(v, d);
                    if (lane >= d) v += u;
                }
                if (lane == 63) wscan[wid] = v;
                __syncthreads();
                if (wid == 0) {
                    int u = (lane < 16) ? wscan[lane] : 0;
#pragma unroll
                    for (int d = 1; d < 16; d <<= 1) {
                        int u2 = __shfl_up(u, d);
                        if (lane >= d) u += u2;
                    }
                    if (lane < 16) wscan[lane] = u;
                }
                __syncthreads();
                if (t < BUCKET_SZ) base1[t] = v + ((wid > 0) ? wscan[wid - 1] : 0);
            }
            __syncthreads();
#pragma unroll
            for (int k = 0; k < EPT_S; k++) {
                if (cl[k] >= 0) {
                    int pos = base1[cl[k]] - cnt1[cl[k]] + lofs[k];
                    if (pos >= 0 && pos < CAP) stage[pos] = ed[k];
                }
            }
            __syncthreads();
            for (int i = t; i < len; i += NTHR) {
                int2 v = stage[i];
                unsigned wb = bf16rne(__int_as_float(v.y));
                ebuf4[s + i] = (wb << 17) | (unsigned)(v.x & 0x1FFFF);
            }
            // degree -> dinv: 8 threads/node + shfl reduce
            {
                int n = t >> 3, l = t & 7;
                int st = base1[n] - cnt1[n], cn = cnt1[n];
                float sum = 0.f;
                for (int i = l; i < cn; i += 8) sum += __int_as_float(stage[st + i].y);
                sum += __shfl_xor(sum, 1);
                sum += __shfl_xor(sum, 2);
                sum += __shfl_xor(sum, 4);
                if (l == 0) {
                    float di = rsqrtf(sum + 1.0f);
                    sdinv[n] = di;
                    int c = nbase + n;
                    if (c < N_NODES) {
                        rp[c] = make_int2(s + st, cn);
                        dinv[c] = di;
                    }
                }
            }
            __syncthreads();                           // stage reads done
            // fused xw1
            {
                const float4* x4 = (const float4*)(x + (size_t)nbase * F_IN);
                const int nv4 = (BUCKET_SZ * F_IN) / 4;
                int gf0 = nbase * F_IN;
                for (int idx = t; idx < nv4; idx += NTHR) {
                    int gf = gf0 + 4 * idx;
                    float4 v;
                    if (gf + 3 < N_NODES * F_IN) {
                        v = x4[idx];
                    } else {
                        v.x = (gf + 0 < N_NODES * F_IN) ? x[gf + 0] : 0.f;
                        v.y = (gf + 1 < N_NODES * F_IN) ? x[gf + 1] : 0.f;
                        v.z = (gf + 2 < N_NODES * F_IN) ? x[gf + 2] : 0.f;
                        v.w = (gf + 3 < N_NODES * F_IN) ? x[gf + 3] : 0.f;
                    }
                    ((float4*)xs)[idx] = v;
                }
            }
            __syncthreads();
            {
                int n = t >> 3, sub = t & 7;
                int c = nbase + n;
                if (c < N_NODES) {
                    const float* xi = &xs[n * F_IN];
                    float a0 = 0.f, a1 = 0.f;
                    for (int k = 0; k < F_IN; k++) {
                        float xv = xi[k];
                        a0 += xv * sW[k * H_DIM + 2 * sub];
                        a1 += xv * sW[k * H_DIM + 2 * sub + 1];
                    }
                    float di = sdinv[n];
                    unsigned pk = bf16rne(di * a0) | (bf16rne(di * a1) << 16);
                    h1b[(size_t)c * 8 + sub] = pk;
                }
            }
        }
    }
    gridbar(bar, 1);

    // ================= P2: layer-1 aggregate (8 lanes/node, grid-stride) ======
    {
        float* sW2 = (float*)(smem + SMEM_A);          // 32
        float* sb1 = sW2 + H_DIM * C_DIM;              // 16
        if (t < H_DIM * C_DIM) sW2[t] = W2[t];
        if (t >= 64 && t < 64 + H_DIM) sb1[t - 64] = b1[t - 64];
        __syncthreads();
        const uint4* h1b4 = (const uint4*)h1b;
        int gid = blockIdx.x * NTHR + t;

        for (int id = gid; id < 8 * N_NODES; id += NPBLK * NTHR) {
            int c = id >> 3, sub = id & 7;
            int2 seg = rp[c];
            int s = seg.x, n = seg.y;
            int m = (n - sub + 7) >> 3;
            int p0i = s + sub;
            float acc[16];
#pragma unroll
            for (int j = 0; j < 16; j++) acc[j] = 0.f;

#define PROC1(u)                                                    \
    {   float a = EW(u);                                            \
        size_t rr = (size_t)ER(u) * 2;                              \
        uint4 g0 = h1b4[rr];                                        \
        uint4 g1 = h1b4[rr + 1];                                    \
        acc[0]  += a * BLO(g0.x); acc[1]  += a * BHI(g0.x);         \
        acc[2]  += a * BLO(g0.y); acc[3]  += a * BHI(g0.y);         \
        acc[4]  += a * BLO(g0.z); acc[5]  += a * BHI(g0.z);         \
        acc[6]  += a * BLO(g0.w); acc[7]  += a * BHI(g0.w);         \
        acc[8]  += a * BLO(g1.x); acc[9]  += a * BHI(g1.x);         \
        acc[10] += a * BLO(g1.y); acc[11] += a * BHI(g1.y);         \
        acc[12] += a * BLO(g1.z); acc[13] += a * BHI(g1.z);         \
        acc[14] += a * BLO(g1.w); acc[15] += a * BHI(g1.w); }

            int k = 0;
            if (m >= 4) {
                unsigned e0 = ebuf4[p0i + 0];
                unsigned e1 = ebuf4[p0i + 8];
                unsigned e2 = ebuf4[p0i + 16];
                unsigned e3 = ebuf4[p0i + 24];
                for (; k + 8 <= m; k += 4) {
                    unsigned f0 = ebuf4[p0i + 8 * (k + 4)];
                    unsigned f1 = ebuf4[p0i + 8 * (k + 5)];
                    unsigned f2 = ebuf4[p0i + 8 * (k + 6)];
                    unsigned f3 = ebuf4[p0i + 8 * (k + 7)];
                    PROC1(e0); PROC1(e1); PROC1(e2); PROC1(e3);
                    e0 = f0; e1 = f1; e2 = f2; e3 = f3;
                }
                PROC1(e0); PROC1(e1); PROC1(e2); PROC1(e3);
                k += 4;
            }
            for (; k < m; k++) {
                unsigned u = ebuf4[p0i + 8 * k];
                PROC1(u);
            }
#undef PROC1

#pragma unroll
            for (int j = 0; j < 16; j++) {
                acc[j] += __shfl_xor(acc[j], 1);
                acc[j] += __shfl_xor(acc[j], 2);
                acc[j] += __shfl_xor(acc[j], 4);
            }
            float dc = dinv[c];
            unsigned gs = h1b[(size_t)c * 8 + sub];
            float r0 = fmaxf(dc * (acc[2 * sub]     + BLO(gs)) + sb1[2 * sub],     0.f);
            float r1 = fmaxf(dc * (acc[2 * sub + 1] + BHI(gs)) + sb1[2 * sub + 1], 0.f);
            float p0 = r0 * sW2[(2 * sub) * C_DIM + 0] + r1 * sW2[(2 * sub + 1) * C_DIM + 0];
            float p1 = r0 * sW2[(2 * sub) * C_DIM + 1] + r1 * sW2[(2 * sub + 1) * C_DIM + 1];
            p0 += __shfl_xor(p0, 1); p0 += __shfl_xor(p0, 2); p0 += __shfl_xor(p0, 4);
            p1 += __shfl_xor(p1, 1); p1 += __shfl_xor(p1, 2); p1 += __shfl_xor(p1, 4);
            if (sub == 0) ((float2*)h2s)[c] = make_float2(dc * p0, dc * p1);
        }
    }
    gridbar(bar, 2);

    // ================= P3: layer-2 aggregate + log_softmax ====================
    {
        const float2* h22 = (const float2*)h2s;
        int gid = blockIdx.x * NTHR + t;
        for (int id = gid; id < 8 * N_NODES; id += NPBLK * NTHR) {
            int c = id >> 3, sub = id & 7;
            int2 seg = rp[c];
            int s = seg.x, n = seg.y;
            int m = (n - sub + 7) >> 3;
            int p0i = s + sub;
            float a0 = 0.f, a1 = 0.f;

#define PROC2(u)                                                    \
    {   float a = EW(u);                                            \
        float2 hv = h22[ER(u)];                                     \
        a0 += a * hv.x;  a1 += a * hv.y; }

            int k = 0;
            if (m >= 4) {
                unsigned e0 = ebuf4[p0i + 0];
                unsigned e1 = ebuf4[p0i + 8];
                unsigned e2 = ebuf4[p0i + 16];
                unsigned e3 = ebuf4[p0i + 24];
                for (; k + 8 <= m; k += 4) {
                    unsigned f0 = ebuf4[p0i + 8 * (k + 4)];
                    unsigned f1 = ebuf4[p0i + 8 * (k + 5)];
                    unsigned f2 = ebuf4[p0i + 8 * (k + 6)];
                    unsigned f3 = ebuf4[p0i + 8 * (k + 7)];
                    PROC2(e0); PROC2(e1); PROC2(e2); PROC2(e3);
                    e0 = f0; e1 = f1; e2 = f2; e3 = f3;
                }
                PROC2(e0); PROC2(e1); PROC2(e2); PROC2(e3);
                k += 4;
            }
            for (; k < m; k++) {
                unsigned u = ebuf4[p0i + 8 * k];
                PROC2(u);
            }
#undef PROC2

            a0 += __shfl_xor(a0, 1); a0 += __shfl_xor(a0, 2); a0 += __shfl_xor(a0, 4);
            a1 += __shfl_xor(a1, 1); a1 += __shfl_xor(a1, 2); a1 += __shfl_xor(a1, 4);
            if (sub == 0) {
                float dc = dinv[c];
                float2 hc = h22[c];
                float l0 = dc * (a0 + hc.x) + b2[0];
                float l1 = dc * (a1 + hc.y) + b2[1];
                float mx = fmaxf(l0, l1);
                float lse = mx + logf(expf(l0 - mx) + expf(l1 - mx));
                ((float2*)out)[c] = make_float2(l0 - lse, l1 - lse);
            }
        }
    }
}

extern "C" void kernel_launch(void* const* d_in, const int* in_sizes, int n_in,
                              void* d_out, int out_size, void* d_ws, size_t ws_size,
                              hipStream_t stream) {
    const float* x  = (const float*)d_in[0];
    const int*   ei = (const int*)d_in[1];     // [2, E]: row then col
    const float* w  = (const float*)d_in[2];
    const float* W1 = (const float*)d_in[3];
    const float* b1 = (const float*)d_in[4];
    const float* W2 = (const float*)d_in[5];
    const float* b2 = (const float*)d_in[6];
    float* out = (float*)d_out;

    const int* row = ei;
    const int* col = ei + N_EDGES;

    // workspace layout (64B-aligned offsets)
    char* ws = (char*)d_ws;
    int*      gcur  = (int*)(ws + 0);            //     3,200 B
    int*      bar   = (int*)(ws + 3200);         //        64 B (barrier counters)
    int2*     rp    = (int2*)(ws + 3264);        //   800,000 B
    float*    dinv  = (float*)(ws + 803264);     //   400,000 B
    unsigned* h1b   = (unsigned*)(ws + 1203264); // 3,200,000 B (bf16 16/row)
    float*    h2s   = (float*)(ws + 4403264);    //   800,000 B
    unsigned* ebuf4 = (unsigned*)(ws + 5203264); //14,814,208 B (782*4736*4)
    int2*     ebuf  = (int2*)(ws + 20017472);    //29,678,416 B (EBUF_SLOTS*8)
    // end: 49,695,888 B

    hipMemsetAsync(ws, 0, 3264, stream);         // gcur + barrier counters = 0

    k_fused<<<NPBLK, NTHR, 0, stream>>>(
        row, col, w, gcur, bar, ebuf, x, W1, ebuf4, rp, dinv,
        h1b, h2s, b1, W2, b2, out);
}

// Round 11
// 671.558 us; speedup vs baseline: 2.0843x; 2.0843x over previous
//
#include <hip/hip_runtime.h>
#include <math.h>

#define N_NODES 100000
#define N_EDGES 3200000
#define F_IN    37
#define H_DIM   16
#define C_DIM   2

#define BUCKET_BITS 7
#define BUCKET_SZ   128
#define NBUCK       782          // ceil(100000/128)
#define CAP         4736         // bucket capacity: mean ~4092 + 10 sigma
#define NPBLK       256          // 1 block/CU, all co-resident (see barrier)
#define NTHR        1024
#define NCHUNK      512          // P0 chunks (2 per block)
#define EB          6250         // edges per P0 chunk (512*6250 = 3.2M exactly)
#define EPT_P       7            // ceil(6250/1024)
#define EPT_S       5            // ceil(CAP/1024)
#define NPAGE       782          // ceil(EB/8) pages for sweep lookup
#define EBUF_SLOTS  (NBUCK * CAP + EB)

// LDS layout: one flat block, phase-aliased.
#define SMEM_A      50048        // region A: P0 stage (50000) / P1 stage/xs
#define SMEM_TOTAL  61072        // + aux region (max 11012 for P0)

__device__ __forceinline__ unsigned bf16rne(float f) {
    unsigned u = __float_as_uint(f);
    return (u + 0x7FFFu + ((u >> 16) & 1u)) >> 16;
}
__device__ __forceinline__ int2 ldnt_i2(const int2* p) {
    long long v = __builtin_nontemporal_load((const long long*)p);
    return *(int2*)&v;
}
#define BLO(u) __uint_as_float((u) << 16)
#define BHI(u) __uint_as_float((u) & 0xFFFF0000u)
// compact edge decode: u = (w_bf16 << 17) | row   (w in [0,1) => sign bit 0)
#define EW(u)  __uint_as_float(((u) >> 17) << 16)
#define ER(u)  ((u) & 0x1FFFFu)

// Software grid barrier (graph-capture-safe; coop launch no-ops under capture —
// R8). R9 PROVED this barrier correct (passed, absmax bit-identical); R9's 7x
// slowdown was VGPR spill (VGPR_Count=32, WRITE 250MB of scratch), fixed here
// by launch_bounds(1024,4) -> 128 VGPR. s_sleep(32) cuts poll traffic ~16x
// (R9: ~300 GB/s of device-scope probe loads at s_sleep(2)).
__device__ __forceinline__ void gridbar(int* bar, int idx) {
    __syncthreads();
    __threadfence();                           // release: flush this block's writes
    if (threadIdx.x == 0) {
        __hip_atomic_fetch_add(&bar[idx], 1, __ATOMIC_RELEASE,
                               __HIP_MEMORY_SCOPE_AGENT);
        while (__hip_atomic_load(&bar[idx], __ATOMIC_ACQUIRE,
                                 __HIP_MEMORY_SCOPE_AGENT) < NPBLK)
            __builtin_amdgcn_s_sleep(32);
    }
    __syncthreads();
    __threadfence();                           // acquire: drop stale cache lines
}

__global__ __launch_bounds__(NTHR, 4) void k_fused(
    const int* __restrict__ row, const int* __restrict__ col,
    const float* __restrict__ w, int* __restrict__ gcur, int* __restrict__ bar,
    int2* __restrict__ ebuf, const float* __restrict__ x,
    const float* __restrict__ W1, unsigned* __restrict__ ebuf4,
    int2* __restrict__ rp, float* __restrict__ dinv,
    unsigned* __restrict__ h1b, float* __restrict__ h2s,
    const float* __restrict__ b1, const float* __restrict__ W2,
    const float* __restrict__ b2, float* __restrict__ out)
{
    __shared__ __align__(16) char smem[SMEM_TOTAL];
    int t = threadIdx.x;

    // ================= P0: partition (LDS-staged counting sort -> linear out) =
    // 2 chunks per block (256 blocks x 2 = 512 chunks of 6250 edges).
    {
        int*  cnt   = (int*)(smem + SMEM_A);           // 782
        int*  base  = cnt + NBUCK;                     // 782
        int*  gbase = base + NBUCK;                    // 782
        int*  wscan = gbase + NBUCK;                   // 16
        unsigned short* pg2b = (unsigned short*)(wscan + 16); // 782
        int2* stage = (int2*)smem;                     // EB

        for (int it = 0; it < 2; it++) {
            int cid = blockIdx.x + it * NPBLK;
            size_t e0 = (size_t)cid * EB;
            int bk[EPT_P], lofs[EPT_P];

            __syncthreads();                           // prev iter LDS reads done
            if (t < NBUCK) cnt[t] = 0;
            __syncthreads();
            // pass A: count (keeps register liveness low across the scan)
#pragma unroll
            for (int k = 0; k < EPT_P; k++) {
                int i = k * NTHR + t;
                if (i < EB) {
                    int c = __builtin_nontemporal_load(&col[e0 + i]);
                    int b = (c >> BUCKET_BITS) & 1023;
                    if (b >= NBUCK) b = NBUCK - 1;     // unreachable guard
                    bk[k] = b;
                    lofs[k] = atomicAdd(&cnt[b], 1);
                } else bk[k] = -1;
            }
            __syncthreads();
            // inclusive scan of cnt[782]: per-wave shfl + cross-wave
            {
                int lane = t & 63, wid = t >> 6;
                int v = (t < NBUCK) ? cnt[t] : 0;
#pragma unroll
                for (int d = 1; d < 64; d <<= 1) {
                    int u = __shfl_up(v, d);
                    if (lane >= d) v += u;
                }
                if (lane == 63) wscan[wid] = v;
                __syncthreads();
                if (wid == 0) {
                    int u = (lane < 16) ? wscan[lane] : 0;
#pragma unroll
                    for (int d = 1; d < 16; d <<= 1) {
                        int u2 = __shfl_up(u, d);
                        if (lane >= d) u += u2;
                    }
                    if (lane < 16) wscan[lane] = u;
                }
                __syncthreads();
                if (t < NBUCK) base[t] = v + ((wid > 0) ? wscan[wid - 1] : 0);
            }
            __syncthreads();
            // pass B: reload row/col/w (L3-warm), scatter into LDS bucket-sorted
#pragma unroll
            for (int k = 0; k < EPT_P; k++) {
                if (bk[k] >= 0) {
                    int i = k * NTHR + t;
                    int r = __builtin_nontemporal_load(&row[e0 + i]);
                    int c = __builtin_nontemporal_load(&col[e0 + i]);
                    float wv = __builtin_nontemporal_load(&w[e0 + i]);
                    int pos = base[bk[k]] - cnt[bk[k]] + lofs[k];
                    if (pos >= 0 && pos < EB)          // unreachable guard
                        stage[pos] = make_int2(
                            (r & 0x1FFFF) | ((c & (BUCKET_SZ - 1)) << 17),
                            __float_as_int(wv));
                }
            }
            if (t < NBUCK) {
                int st = base[t] - cnt[t], en = base[t];
                int p0 = (st + 7) >> 3, p1 = (en - 1) >> 3;
                if (p0 < 0) p0 = 0;
                if (p1 >= NPAGE) p1 = NPAGE - 1;       // unreachable guard
                for (int p = p0; p <= p1; p++) pg2b[p] = (unsigned short)t;
                gbase[t] = t * CAP + atomicAdd(&gcur[t], cnt[t]);
            }
            __syncthreads();
            for (int s2 = t; s2 < EB; s2 += NTHR) {
                int lo = pg2b[s2 >> 3];
                while (lo < NBUCK - 1 && base[lo] <= s2) lo++;
                int dst = gbase[lo] + (s2 - (base[lo] - cnt[lo]));
                if (dst >= 0 && dst < EBUF_SLOTS)      // unreachable guard
                    ebuf[dst] = stage[s2];
            }
        }
    }
    gridbar(bar, 0);

    // ================= P1: per-bucket sort -> ebuf4 + rp + dinv + h1b =========
    {
        int*   cnt1  = (int*)(smem + SMEM_A);          // 128
        int*   base1 = cnt1 + BUCKET_SZ;               // 128
        float* sdinv = (float*)(base1 + BUCKET_SZ);    // 128
        int*   wscan = (int*)(sdinv + BUCKET_SZ);      // 16
        float* sW    = (float*)(wscan + 16);           // 592
        int2*  stage = (int2*)smem;                    // CAP
        float* xs    = (float*)smem;                   // aliased after sort use

        __syncthreads();                               // P0 stage reads done
        for (int idx = t; idx < F_IN * H_DIM; idx += NTHR) sW[idx] = W1[idx];

        for (int b = blockIdx.x; b < NBUCK; b += NPBLK) {
            int s = b * CAP;
            int len = gcur[b];
            if (len > CAP) len = CAP;                  // unreachable guard
            int nbase = b << BUCKET_BITS;
            __syncthreads();                           // xs/stage free, sW ready
            if (t < BUCKET_SZ) cnt1[t] = 0;
            __syncthreads();

            int2 ed[EPT_S]; int cl[EPT_S], lofs[EPT_S];
#pragma unroll
            for (int k = 0; k < EPT_S; k++) {
                int i = k * NTHR + t;
                if (i < len) {
                    int2 v = ldnt_i2(&ebuf[s + i]);
                    ed[k] = v;
                    cl[k] = (v.x >> 17) & (BUCKET_SZ - 1);
                    lofs[k] = atomicAdd(&cnt1[cl[k]], 1);
                } else cl[k] = -1;
            }
            __syncthreads();
            // scan of cnt1[128]
            {
                int lane = t & 63, wid = t >> 6;
                int v = (t < BUCKET_SZ) ? cnt1[t] : 0;
#pragma unroll
                for (int d = 1; d < 64; d <<= 1) {
                    int u = __shfl_up(v, d);
                    if (lane >= d) v += u;
                }
                if (lane == 63) wscan[wid] = v;
                __syncthreads();
                if (wid == 0) {
                    int u = (lane < 16) ? wscan[lane] : 0;
#pragma unroll
                    for (int d = 1; d < 16; d <<= 1) {
                        int u2 = __shfl_up(u, d);
                        if (lane >= d) u += u2;
                    }
                    if (lane < 16) wscan[lane] = u;
                }
                __syncthreads();
                if (t < BUCKET_SZ) base1[t] = v + ((wid > 0) ? wscan[wid - 1] : 0);
            }
            __syncthreads();
#pragma unroll
            for (int k = 0; k < EPT_S; k++) {
                if (cl[k] >= 0) {
                    int pos = base1[cl[k]] - cnt1[cl[k]] + lofs[k];
                    if (pos >= 0 && pos < CAP) stage[pos] = ed[k];
                }
            }
            __syncthreads();
            for (int i = t; i < len; i += NTHR) {
                int2 v = stage[i];
                unsigned wb = bf16rne(__int_as_float(v.y));
                __builtin_nontemporal_store((wb << 17) | (unsigned)(v.x & 0x1FFFF),
                                            &ebuf4[s + i]);
            }
            // degree -> dinv: 8 threads/node + shfl reduce
            {
                int n = t >> 3, l = t & 7;
                int st = base1[n] - cnt1[n], cn = cnt1[n];
                float sum = 0.f;
                for (int i = l; i < cn; i += 8) sum += __int_as_float(stage[st + i].y);
                sum += __shfl_xor(sum, 1);
                sum += __shfl_xor(sum, 2);
                sum += __shfl_xor(sum, 4);
                if (l == 0) {
                    float di = rsqrtf(sum + 1.0f);
                    sdinv[n] = di;
                    int c = nbase + n;
                    if (c < N_NODES) {
                        rp[c] = make_int2(s + st, cn);
                        dinv[c] = di;
                    }
                }
            }
            __syncthreads();                           // stage reads done
            // fused xw1
            {
                const float4* x4 = (const float4*)(x + (size_t)nbase * F_IN);
                const int nv4 = (BUCKET_SZ * F_IN) / 4;
                int gf0 = nbase * F_IN;
                for (int idx = t; idx < nv4; idx += NTHR) {
                    int gf = gf0 + 4 * idx;
                    float4 v;
                    if (gf + 3 < N_NODES * F_IN) {
                        v = x4[idx];
                    } else {
                        v.x = (gf + 0 < N_NODES * F_IN) ? x[gf + 0] : 0.f;
                        v.y = (gf + 1 < N_NODES * F_IN) ? x[gf + 1] : 0.f;
                        v.z = (gf + 2 < N_NODES * F_IN) ? x[gf + 2] : 0.f;
                        v.w = (gf + 3 < N_NODES * F_IN) ? x[gf + 3] : 0.f;
                    }
                    ((float4*)xs)[idx] = v;
                }
            }
            __syncthreads();
            {
                int n = t >> 3, sub = t & 7;
                int c = nbase + n;
                if (c < N_NODES) {
                    const float* xi = &xs[n * F_IN];
                    float a0 = 0.f, a1 = 0.f;
                    for (int k = 0; k < F_IN; k++) {
                        float xv = xi[k];
                        a0 += xv * sW[k * H_DIM + 2 * sub];
                        a1 += xv * sW[k * H_DIM + 2 * sub + 1];
                    }
                    float di = sdinv[n];
                    unsigned pk = bf16rne(di * a0) | (bf16rne(di * a1) << 16);
                    h1b[(size_t)c * 8 + sub] = pk;
                }
            }
        }
    }
    gridbar(bar, 1);

    // ================= P2: layer-1 aggregate (8 lanes/node, grid-stride) ======
    {
        float* sW2 = (float*)(smem + SMEM_A);          // 32
        float* sb1 = sW2 + H_DIM * C_DIM;              // 16
        __syncthreads();
        if (t < H_DIM * C_DIM) sW2[t] = W2[t];
        if (t >= 64 && t < 64 + H_DIM) sb1[t - 64] = b1[t - 64];
        __syncthreads();
        const uint4* h1b4 = (const uint4*)h1b;
        int gid = blockIdx.x * NTHR + t;

        for (int id = gid; id < 8 * N_NODES; id += NPBLK * NTHR) {
            int c = id >> 3, sub = id & 7;
            int2 seg = rp[c];
            int s = seg.x, n = seg.y;
            int m = (n - sub + 7) >> 3;
            int p0i = s + sub;
            float acc[16];
#pragma unroll
            for (int j = 0; j < 16; j++) acc[j] = 0.f;

#define PROC1(u)                                                    \
    {   float a = EW(u);                                            \
        size_t rr = (size_t)ER(u) * 2;                              \
        uint4 g0 = h1b4[rr];                                        \
        uint4 g1 = h1b4[rr + 1];                                    \
        acc[0]  += a * BLO(g0.x); acc[1]  += a * BHI(g0.x);         \
        acc[2]  += a * BLO(g0.y); acc[3]  += a * BHI(g0.y);         \
        acc[4]  += a * BLO(g0.z); acc[5]  += a * BHI(g0.z);         \
        acc[6]  += a * BLO(g0.w); acc[7]  += a * BHI(g0.w);         \
        acc[8]  += a * BLO(g1.x); acc[9]  += a * BHI(g1.x);         \
        acc[10] += a * BLO(g1.y); acc[11] += a * BHI(g1.y);         \
        acc[12] += a * BLO(g1.z); acc[13] += a * BHI(g1.z);         \
        acc[14] += a * BLO(g1.w); acc[15] += a * BHI(g1.w); }

            int k = 0;
            if (m >= 4) {
                unsigned e0 = __builtin_nontemporal_load(&ebuf4[p0i + 0]);
                unsigned e1 = __builtin_nontemporal_load(&ebuf4[p0i + 8]);
                unsigned e2 = __builtin_nontemporal_load(&ebuf4[p0i + 16]);
                unsigned e3 = __builtin_nontemporal_load(&ebuf4[p0i + 24]);
                for (; k + 8 <= m; k += 4) {
                    unsigned f0 = __builtin_nontemporal_load(&ebuf4[p0i + 8 * (k + 4)]);
                    unsigned f1 = __builtin_nontemporal_load(&ebuf4[p0i + 8 * (k + 5)]);
                    unsigned f2 = __builtin_nontemporal_load(&ebuf4[p0i + 8 * (k + 6)]);
                    unsigned f3 = __builtin_nontemporal_load(&ebuf4[p0i + 8 * (k + 7)]);
                    PROC1(e0); PROC1(e1); PROC1(e2); PROC1(e3);
                    e0 = f0; e1 = f1; e2 = f2; e3 = f3;
                }
                PROC1(e0); PROC1(e1); PROC1(e2); PROC1(e3);
                k += 4;
            }
            for (; k < m; k++) {
                unsigned u = __builtin_nontemporal_load(&ebuf4[p0i + 8 * k]);
                PROC1(u);
            }
#undef PROC1

#pragma unroll
            for (int j = 0; j < 16; j++) {
                acc[j] += __shfl_xor(acc[j], 1);
                acc[j] += __shfl_xor(acc[j], 2);
                acc[j] += __shfl_xor(acc[j], 4);
            }
            float dc = dinv[c];
            unsigned gs = h1b[(size_t)c * 8 + sub];
            float r0 = fmaxf(dc * (acc[2 * sub]     + BLO(gs)) + sb1[2 * sub],     0.f);
            float r1 = fmaxf(dc * (acc[2 * sub + 1] + BHI(gs)) + sb1[2 * sub + 1], 0.f);
            float p0 = r0 * sW2[(2 * sub) * C_DIM + 0] + r1 * sW2[(2 * sub + 1) * C_DIM + 0];
            float p1 = r0 * sW2[(2 * sub) * C_DIM + 1] + r1 * sW2[(2 * sub + 1) * C_DIM + 1];
            p0 += __shfl_xor(p0, 1); p0 += __shfl_xor(p0, 2); p0 += __shfl_xor(p0, 4);
            p1 += __shfl_xor(p1, 1); p1 += __shfl_xor(p1, 2); p1 += __shfl_xor(p1, 4);
            if (sub == 0) ((float2*)h2s)[c] = make_float2(dc * p0, dc * p1);
        }
    }
    gridbar(bar, 2);

    // ================= P3: layer-2 aggregate + log_softmax ====================
    {
        const float2* h22 = (const float2*)h2s;
        int gid = blockIdx.x * NTHR + t;
        for (int id = gid; id < 8 * N_NODES; id += NPBLK * NTHR) {
            int c = id >> 3, sub = id & 7;
            int2 seg = rp[c];
            int s = seg.x, n = seg.y;
            int m = (n - sub + 7) >> 3;
            int p0i = s + sub;
            float a0 = 0.f, a1 = 0.f;

#define PROC2(u)                                                    \
    {   float a = EW(u);                                            \
        float2 hv = h22[ER(u)];                                     \
        a0 += a * hv.x;  a1 += a * hv.y; }

            int k = 0;
            if (m >= 4) {
                unsigned e0 = __builtin_nontemporal_load(&ebuf4[p0i + 0]);
                unsigned e1 = __builtin_nontemporal_load(&ebuf4[p0i + 8]);
                unsigned e2 = __builtin_nontemporal_load(&ebuf4[p0i + 16]);
                unsigned e3 = __builtin_nontemporal_load(&ebuf4[p0i + 24]);
                for (; k + 8 <= m; k += 4) {
                    unsigned f0 = __builtin_nontemporal_load(&ebuf4[p0i + 8 * (k + 4)]);
                    unsigned f1 = __builtin_nontemporal_load(&ebuf4[p0i + 8 * (k + 5)]);
                    unsigned f2 = __builtin_nontemporal_load(&ebuf4[p0i + 8 * (k + 6)]);
                    unsigned f3 = __builtin_nontemporal_load(&ebuf4[p0i + 8 * (k + 7)]);
                    PROC2(e0); PROC2(e1); PROC2(e2); PROC2(e3);
                    e0 = f0; e1 = f1; e2 = f2; e3 = f3;
                }
                PROC2(e0); PROC2(e1); PROC2(e2); PROC2(e3);
                k += 4;
            }
            for (; k < m; k++) {
                unsigned u = __builtin_nontemporal_load(&ebuf4[p0i + 8 * k]);
                PROC2(u);
            }
#undef PROC2

            a0 += __shfl_xor(a0, 1); a0 += __shfl_xor(a0, 2); a0 += __shfl_xor(a0, 4);
            a1 += __shfl_xor(a1, 1); a1 += __shfl_xor(a1, 2); a1 += __shfl_xor(a1, 4);
            if (sub == 0) {
                float dc = dinv[c];
                float2 hc = h22[c];
                float l0 = dc * (a0 + hc.x) + b2[0];
                float l1 = dc * (a1 + hc.y) + b2[1];
                float mx = fmaxf(l0, l1);
                float lse = mx + logf(expf(l0 - mx) + expf(l1 - mx));
                ((float2*)out)[c] = make_float2(l0 - lse, l1 - lse);
            }
        }
    }
}

extern "C" void kernel_launch(void* const* d_in, const int* in_sizes, int n_in,
                              void* d_out, int out_size, void* d_ws, size_t ws_size,
                              hipStream_t stream) {
    const float* x  = (const float*)d_in[0];
    const int*   ei = (const int*)d_in[1];     // [2, E]: row then col
    const float* w  = (const float*)d_in[2];
    const float* W1 = (const float*)d_in[3];
    const float* b1 = (const float*)d_in[4];
    const float* W2 = (const float*)d_in[5];
    const float* b2 = (const float*)d_in[6];
    float* out = (float*)d_out;

    const int* row = ei;
    const int* col = ei + N_EDGES;

    // workspace layout (64B-aligned offsets)
    char* ws = (char*)d_ws;
    int*      gcur  = (int*)(ws + 0);            //     3,200 B
    int*      bar   = (int*)(ws + 3200);         //        64 B (barrier counters)
    int2*     rp    = (int2*)(ws + 3264);        //   800,000 B
    float*    dinv  = (float*)(ws + 803264);     //   400,000 B
    unsigned* h1b   = (unsigned*)(ws + 1203264); // 3,200,000 B (bf16 16/row)
    float*    h2s   = (float*)(ws + 4403264);    //   800,000 B
    unsigned* ebuf4 = (unsigned*)(ws + 5203264); //14,814,208 B (782*4736*4)
    int2*     ebuf  = (int2*)(ws + 20017472);    //29,678,416 B (EBUF_SLOTS*8)
    // end: 49,695,888 B

    hipMemsetAsync(ws, 0, 3264, stream);         // gcur + barrier counters = 0

    k_fused<<<NPBLK, NTHR, 0, stream>>>(
        row, col, w, gcur, bar, ebuf, x, W1, ebuf4, rp, dinv,
        h1b, h2s, b1, W2, b2, out);
}

// Round 12
// 199.032 us; speedup vs baseline: 7.0326x; 3.3741x over previous
//
#include <hip/hip_runtime.h>
#include <math.h>

#define N_NODES 100000
#define N_EDGES 3200000
#define F_IN    37
#define H_DIM   16
#define C_DIM   2

#define BUCKET_BITS 7
#define BUCKET_SZ   128
#define NBUCK       782          // ceil(100000/128)
#define CAP         4736         // bucket capacity: mean ~4092 + 10 sigma
#define NPBLK       512          // k_part grid (2 blocks/CU)
#define EB          6250         // edges per part block (512*6250 = 3.2M exactly)
#define EPT_P       7            // ceil(6250/1024)
#define EPT_S       5            // ceil(CAP/1024)
#define NPAGE       782          // ceil(EB/8) pages for sweep lookup
#define EBUF_SLOTS  (NBUCK * CAP + EB)   // +slack so clamped writes stay in-buffer

__device__ __forceinline__ unsigned bf16rne(float f) {
    unsigned u = __float_as_uint(f);
    return (u + 0x7FFFu + ((u >> 16) & 1u)) >> 16;
}
__device__ __forceinline__ int2 ldnt_i2(const int2* p) {
    long long v = __builtin_nontemporal_load((const long long*)p);
    return *(int2*)&v;
}
#define BLO(u) __uint_as_float((u) << 16)
#define BHI(u) __uint_as_float((u) & 0xFFFF0000u)
// compact edge decode: u = (w_bf16 << 17) | row   (w in [0,1) => sign bit 0)
#define EW(u)  __uint_as_float(((u) >> 17) << 16)
#define ER(u)  ((u) & 0x1FFFFu)

// ---------- partition: LDS-staged counting sort per chunk -> linear write-out.
// (Proven at 191.0us twice: R1 and R7. VERBATIM.)
__global__ __launch_bounds__(1024) void k_part(
    const int* __restrict__ row, const int* __restrict__ col,
    const float* __restrict__ w, int* __restrict__ gcur, int2* __restrict__ ebuf)
{
    __shared__ int  cnt[NBUCK];
    __shared__ int  base[NBUCK];               // inclusive scan
    __shared__ int  gbase[NBUCK];
    __shared__ int  wscan[16];                 // per-wave scan sums
    __shared__ unsigned short pg2b[NPAGE];     // page -> bucket containing 8p
    __shared__ int2 stage[EB];                 // 50 KB
    int t = threadIdx.x;
    size_t e0 = (size_t)blockIdx.x * EB;
    int bk[EPT_P], rc[EPT_P], lofs[EPT_P];
    float wv[EPT_P];

    if (t < NBUCK) cnt[t] = 0;
    __syncthreads();
#pragma unroll
    for (int k = 0; k < EPT_P; k++) {
        int i = k * 1024 + t;
        if (i < EB) {
            size_t e = e0 + i;
            int r = __builtin_nontemporal_load(&row[e]);
            int c = __builtin_nontemporal_load(&col[e]);
            wv[k] = __builtin_nontemporal_load(&w[e]);
            bk[k] = (c >> BUCKET_BITS) & 1023;         // clamp-mask (c<2^17 anyway)
            if (bk[k] >= NBUCK) bk[k] = NBUCK - 1;     // unreachable guard
            rc[k] = (r & 0x1FFFF) | ((c & (BUCKET_SZ - 1)) << 17);
            lofs[k] = atomicAdd(&cnt[bk[k]], 1);
        } else bk[k] = -1;
    }
    __syncthreads();
    // ---- inclusive scan of cnt[782]: per-wave shfl scan + cross-wave ----
    {
        int lane = t & 63, wid = t >> 6;
        int v = (t < NBUCK) ? cnt[t] : 0;
#pragma unroll
        for (int d = 1; d < 64; d <<= 1) {
            int u = __shfl_up(v, d);
            if (lane >= d) v += u;
        }
        if (lane == 63) wscan[wid] = v;
        __syncthreads();
        if (wid == 0) {
            int u = (lane < 16) ? wscan[lane] : 0;
#pragma unroll
            for (int d = 1; d < 16; d <<= 1) {
                int u2 = __shfl_up(u, d);
                if (lane >= d) u += u2;
            }
            if (lane < 16) wscan[lane] = u;    // inclusive scan of wave sums
        }
        __syncthreads();
        if (t < NBUCK) base[t] = v + ((wid > 0) ? wscan[wid - 1] : 0);
    }
    __syncthreads();
    // scatter into LDS stage, bucket-sorted; build page->bucket table
#pragma unroll
    for (int k = 0; k < EPT_P; k++) {
        if (bk[k] >= 0) {
            int pos = base[bk[k]] - cnt[bk[k]] + lofs[k];
            if (pos >= 0 && pos < EB) stage[pos] =     // unreachable guard
                make_int2(rc[k], __float_as_int(wv[k]));
        }
    }
    if (t < NBUCK) {
        int st = base[t] - cnt[t], en = base[t];
        int p0 = (st + 7) >> 3, p1 = (en - 1) >> 3;
        if (p0 < 0) p0 = 0;
        if (p1 >= NPAGE) p1 = NPAGE - 1;               // unreachable guard
        for (int p = p0; p <= p1; p++)
            pg2b[p] = (unsigned short)t;       // unique containing bucket per page
        gbase[t] = t * CAP + atomicAdd(&gcur[t], cnt[t]);
    }
    __syncthreads();
    // linear sweep write-out (stride-1024: coalesced full-line writes)
    for (int s2 = t; s2 < EB; s2 += 1024) {
        int lo = pg2b[s2 >> 3];
        while (lo < NBUCK - 1 && base[lo] <= s2) lo++; // bounded walk
        int dst = gbase[lo] + (s2 - (base[lo] - cnt[lo]));
        if (dst >= 0 && dst < EBUF_SLOTS)              // unreachable guard
            ebuf[dst] = stage[s2];
    }
}

// ---------- fused: per-bucket LDS counting sort -> compact 4B edges + CSR
//            + dinv + h1b = bf16(dinv * (x @ W1)). (Proven at 191.0us. VERBATIM.)
__global__ __launch_bounds__(1024) void k_sortxw1(
    const int* __restrict__ gcur, const int2* __restrict__ ebuf,
    const float* __restrict__ x, const float* __restrict__ W1,
    unsigned* __restrict__ ebuf4, int2* __restrict__ rp,
    float* __restrict__ dinv, unsigned* __restrict__ h1b)
{
    __shared__ int2  stage[CAP];              // 37.9 KB (reused as xs below)
    __shared__ int   cnt[BUCKET_SZ];
    __shared__ int   base[BUCKET_SZ];
    __shared__ float sdinv[BUCKET_SZ];
    __shared__ int   wscan[16];
    __shared__ float sW[F_IN * H_DIM];        // 2.4 KB
    float* xs = (float*)stage;                // aliased reuse: 128*37 floats

    int t = threadIdx.x, b = blockIdx.x;
    int s = b * CAP;
    int len = gcur[b];
    if (len > CAP) len = CAP;                 // unreachable guard
    int nbase = b << BUCKET_BITS;
    if (t < BUCKET_SZ) cnt[t] = 0;
    __syncthreads();

    // ---- load + count ----
    int2 ed[EPT_S]; int cl[EPT_S], lofs[EPT_S];
#pragma unroll
    for (int k = 0; k < EPT_S; k++) {
        int i = k * 1024 + t;
        if (i < len) {
            int2 v = ldnt_i2(&ebuf[s + i]);
            ed[k] = v;
            cl[k] = (v.x >> 17) & (BUCKET_SZ - 1);
            lofs[k] = atomicAdd(&cnt[cl[k]], 1);
        } else cl[k] = -1;
    }
    __syncthreads();
    // ---- inclusive scan of cnt[128]: per-wave shfl scan + cross-wave ----
    {
        int lane = t & 63, wid = t >> 6;
        int v = (t < BUCKET_SZ) ? cnt[t] : 0;
#pragma unroll
        for (int d = 1; d < 64; d <<= 1) {
            int u = __shfl_up(v, d);
            if (lane >= d) v += u;
        }
        if (lane == 63) wscan[wid] = v;
        __syncthreads();
        if (wid == 0) {
            int u = (lane < 16) ? wscan[lane] : 0;
#pragma unroll
            for (int d = 1; d < 16; d <<= 1) {
                int u2 = __shfl_up(u, d);
                if (lane >= d) u += u2;
            }
            if (lane < 16) wscan[lane] = u;
        }
        __syncthreads();
        if (t < BUCKET_SZ) base[t] = v + ((wid > 0) ? wscan[wid - 1] : 0);
    }
    __syncthreads();
    // ---- scatter into LDS stage in node-sorted order ----
#pragma unroll
    for (int k = 0; k < EPT_S; k++) {
        if (cl[k] >= 0) {
            int pos = base[cl[k]] - cnt[cl[k]] + lofs[k];
            if (pos >= 0 && pos < CAP) stage[pos] = ed[k];   // unreachable guard
        }
    }
    __syncthreads();
    // ---- compact 4B write-back (NT, coalesced => full-line writes) ----
    for (int i = t; i < len; i += 1024) {
        int2 v = stage[i];
        unsigned wb = bf16rne(__int_as_float(v.y));
        __builtin_nontemporal_store((wb << 17) | (unsigned)(v.x & 0x1FFFF),
                                    &ebuf4[s + i]);
    }
    // ---- degree -> dinv: 8 threads/node strided + shfl reduce ----
    {
        int n = t >> 3, l = t & 7;
        int st = base[n] - cnt[n], cn = cnt[n];
        float sum = 0.f;
        for (int i = l; i < cn; i += 8) sum += __int_as_float(stage[st + i].y);
        sum += __shfl_xor(sum, 1);
        sum += __shfl_xor(sum, 2);
        sum += __shfl_xor(sum, 4);
        if (l == 0) {
            float di = rsqrtf(sum + 1.0f);    // + self-loop
            sdinv[n] = di;
            int c = nbase + n;
            if (c < N_NODES) {
                rp[c] = make_int2(s + st, cn);
                dinv[c] = di;
            }
        }
    }
    __syncthreads();                          // stage reads done; xs overwrite ok

    // ---- fused xw1 for this bucket's 128 nodes ----
    for (int idx = t; idx < F_IN * H_DIM; idx += 1024) sW[idx] = W1[idx];
    {
        const float4* x4 = (const float4*)(x + (size_t)nbase * F_IN);
        const int nv4 = (BUCKET_SZ * F_IN) / 4;   // 1184
        int gf0 = nbase * F_IN;
        for (int idx = t; idx < nv4; idx += 1024) {
            int gf = gf0 + 4 * idx;
            float4 v;
            if (gf + 3 < N_NODES * F_IN) {
                v = x4[idx];
            } else {
                v.x = (gf + 0 < N_NODES * F_IN) ? x[gf + 0] : 0.f;
                v.y = (gf + 1 < N_NODES * F_IN) ? x[gf + 1] : 0.f;
                v.z = (gf + 2 < N_NODES * F_IN) ? x[gf + 2] : 0.f;
                v.w = (gf + 3 < N_NODES * F_IN) ? x[gf + 3] : 0.f;
            }
            ((float4*)xs)[idx] = v;
        }
    }
    __syncthreads();
    // 8 threads/node, each computes 2 output cols {2*sub, 2*sub+1}
    {
        int n = t >> 3, sub = t & 7;
        int c = nbase + n;
        if (c < N_NODES) {
            const float* xi = &xs[n * F_IN];
            float a0 = 0.f, a1 = 0.f;
            for (int k = 0; k < F_IN; k++) {
                float xv = xi[k];
                a0 += xv * sW[k * H_DIM + 2 * sub];
                a1 += xv * sW[k * H_DIM + 2 * sub + 1];
            }
            float di = sdinv[n];
            unsigned pk = bf16rne(di * a0) | (bf16rne(di * a1) << 16);
            h1b[(size_t)c * 8 + sub] = pk;    // 32B/node, coalesced
        }
    }
}

// ---------- layer 1: 4 lanes/node (segment quarters, m~8/lane).
// ILP-depth test: R7 proved request COUNT is not the agg bottleneck (16->8
// lanes, 4->3 req/edge: exactly 0 change). The untested knob is per-lane
// pipeline depth: at m~4 the 4-deep prefetch never fills. 4 lanes/node
// doubles per-lane MLP and halves reduce levels. Same bytes, ULP-only reorder.
__global__ __launch_bounds__(256) void k_agg1(
    const int2* __restrict__ rp, const unsigned* __restrict__ ebuf4,
    const uint4* __restrict__ h1b, const float* __restrict__ dinv,
    const float* __restrict__ b1, const float* __restrict__ W2,
    float* __restrict__ h2s)
{
    __shared__ float sW2[H_DIM * C_DIM];
    __shared__ float sb1[H_DIM];
    int t = threadIdx.x;
    if (t < H_DIM * C_DIM) sW2[t] = W2[t];
    if (t >= 32 && t < 32 + H_DIM) sb1[t - 32] = b1[t - 32];
    __syncthreads();
    int id = blockIdx.x * 256 + t;
    int c = id >> 2;                           // 4 lanes per node
    int sub = id & 3;
    if (c >= N_NODES) return;
    int2 seg = rp[c];
    int s = seg.x, n = seg.y;
    int m = (n - sub + 3) >> 2;                // edges for this quarter (stride 4)
    int p0i = s + sub;
    float acc[16];
#pragma unroll
    for (int j = 0; j < 16; j++) acc[j] = 0.f;

#define PROC1(u)                                                    \
    {   float a = EW(u);                                            \
        size_t rr = (size_t)ER(u) * 2;                              \
        uint4 g0 = h1b[rr];                                         \
        uint4 g1 = h1b[rr + 1];                                     \
        acc[0]  += a * BLO(g0.x); acc[1]  += a * BHI(g0.x);         \
        acc[2]  += a * BLO(g0.y); acc[3]  += a * BHI(g0.y);         \
        acc[4]  += a * BLO(g0.z); acc[5]  += a * BHI(g0.z);         \
        acc[6]  += a * BLO(g0.w); acc[7]  += a * BHI(g0.w);         \
        acc[8]  += a * BLO(g1.x); acc[9]  += a * BHI(g1.x);         \
        acc[10] += a * BLO(g1.y); acc[11] += a * BHI(g1.y);         \
        acc[12] += a * BLO(g1.z); acc[13] += a * BHI(g1.z);         \
        acc[14] += a * BLO(g1.w); acc[15] += a * BHI(g1.w); }

    int k = 0;
    if (m >= 4) {
        unsigned e0 = __builtin_nontemporal_load(&ebuf4[p0i + 0]);
        unsigned e1 = __builtin_nontemporal_load(&ebuf4[p0i + 4]);
        unsigned e2 = __builtin_nontemporal_load(&ebuf4[p0i + 8]);
        unsigned e3 = __builtin_nontemporal_load(&ebuf4[p0i + 12]);
        for (; k + 8 <= m; k += 4) {
            unsigned f0 = __builtin_nontemporal_load(&ebuf4[p0i + 4 * (k + 4)]);
            unsigned f1 = __builtin_nontemporal_load(&ebuf4[p0i + 4 * (k + 5)]);
            unsigned f2 = __builtin_nontemporal_load(&ebuf4[p0i + 4 * (k + 6)]);
            unsigned f3 = __builtin_nontemporal_load(&ebuf4[p0i + 4 * (k + 7)]);
            PROC1(e0); PROC1(e1); PROC1(e2); PROC1(e3);
            e0 = f0; e1 = f1; e2 = f2; e3 = f3;
        }
        PROC1(e0); PROC1(e1); PROC1(e2); PROC1(e3);
        k += 4;
    }
    for (; k < m; k++) {
        unsigned u = __builtin_nontemporal_load(&ebuf4[p0i + 4 * k]);
        PROC1(u);
    }
#undef PROC1

    // combine the 4 segment-quarters (2 levels)
#pragma unroll
    for (int j = 0; j < 16; j++) {
        acc[j] += __shfl_xor(acc[j], 1);
        acc[j] += __shfl_xor(acc[j], 2);
    }

    // epilogue: each lane finishes 4 features {4*sub .. 4*sub+3}
    float dc = dinv[c];
    const unsigned* h1w = (const unsigned*)h1b;
    unsigned gs0 = h1w[(size_t)c * 8 + 2 * sub];       // self term, 2 features
    unsigned gs1 = h1w[(size_t)c * 8 + 2 * sub + 1];   // self term, 2 features
    int j0 = 4 * sub;
    float r0 = fmaxf(dc * (acc[j0 + 0] + BLO(gs0)) + sb1[j0 + 0], 0.f);
    float r1 = fmaxf(dc * (acc[j0 + 1] + BHI(gs0)) + sb1[j0 + 1], 0.f);
    float r2 = fmaxf(dc * (acc[j0 + 2] + BLO(gs1)) + sb1[j0 + 2], 0.f);
    float r3 = fmaxf(dc * (acc[j0 + 3] + BHI(gs1)) + sb1[j0 + 3], 0.f);
    float p0 = r0 * sW2[(j0 + 0) * C_DIM + 0] + r1 * sW2[(j0 + 1) * C_DIM + 0]
             + r2 * sW2[(j0 + 2) * C_DIM + 0] + r3 * sW2[(j0 + 3) * C_DIM + 0];
    float p1 = r0 * sW2[(j0 + 0) * C_DIM + 1] + r1 * sW2[(j0 + 1) * C_DIM + 1]
             + r2 * sW2[(j0 + 2) * C_DIM + 1] + r3 * sW2[(j0 + 3) * C_DIM + 1];
    p0 += __shfl_xor(p0, 1); p0 += __shfl_xor(p0, 2);
    p1 += __shfl_xor(p1, 1); p1 += __shfl_xor(p1, 2);
    if (sub == 0) ((float2*)h2s)[c] = make_float2(dc * p0, dc * p1);
}

// ---------- layer 2: 4 lanes/node (segment quarters), shfl reduce,
//            + bias + log_softmax ----------
__global__ __launch_bounds__(256) void k_agg2(
    const int2* __restrict__ rp, const unsigned* __restrict__ ebuf4,
    const float* __restrict__ h2s, const float* __restrict__ dinv,
    const float* __restrict__ b2, float* __restrict__ out)
{
    int id = blockIdx.x * 256 + threadIdx.x;
    int c = id >> 2, sub = id & 3;
    if (c >= N_NODES) return;
    int2 seg = rp[c];
    int s = seg.x, n = seg.y;
    const float2* h22 = (const float2*)h2s;
    int m = (n - sub + 3) >> 2;                // edges for this quarter (stride 4)
    int p0i = s + sub;
    float a0 = 0.f, a1 = 0.f;

#define PROC2(u)                                                    \
    {   float a = EW(u);                                            \
        float2 hv = h22[ER(u)];                                     \
        a0 += a * hv.x;  a1 += a * hv.y; }

    int k = 0;
    if (m >= 4) {
        unsigned e0 = __builtin_nontemporal_load(&ebuf4[p0i + 0]);
        unsigned e1 = __builtin_nontemporal_load(&ebuf4[p0i + 4]);
        unsigned e2 = __builtin_nontemporal_load(&ebuf4[p0i + 8]);
        unsigned e3 = __builtin_nontemporal_load(&ebuf4[p0i + 12]);
        for (; k + 8 <= m; k += 4) {
            unsigned f0 = __builtin_nontemporal_load(&ebuf4[p0i + 4 * (k + 4)]);
            unsigned f1 = __builtin_nontemporal_load(&ebuf4[p0i + 4 * (k + 5)]);
            unsigned f2 = __builtin_nontemporal_load(&ebuf4[p0i + 4 * (k + 6)]);
            unsigned f3 = __builtin_nontemporal_load(&ebuf4[p0i + 4 * (k + 7)]);
            PROC2(e0); PROC2(e1); PROC2(e2); PROC2(e3);
            e0 = f0; e1 = f1; e2 = f2; e3 = f3;
        }
        PROC2(e0); PROC2(e1); PROC2(e2); PROC2(e3);
        k += 4;
    }
    for (; k < m; k++) {
        unsigned u = __builtin_nontemporal_load(&ebuf4[p0i + 4 * k]);
        PROC2(u);
    }
#undef PROC2

    a0 += __shfl_xor(a0, 1); a0 += __shfl_xor(a0, 2);
    a1 += __shfl_xor(a1, 1); a1 += __shfl_xor(a1, 2);
    if (sub == 0) {
        float dc = dinv[c];
        float2 hc = h22[c];
        float l0 = dc * (a0 + hc.x) + b2[0];
        float l1 = dc * (a1 + hc.y) + b2[1];
        float mx = fmaxf(l0, l1);
        float lse = mx + logf(expf(l0 - mx) + expf(l1 - mx));
        ((float2*)out)[c] = make_float2(l0 - lse, l1 - lse);
    }
}

extern "C" void kernel_launch(void* const* d_in, const int* in_sizes, int n_in,
                              void* d_out, int out_size, void* d_ws, size_t ws_size,
                              hipStream_t stream) {
    const float* x  = (const float*)d_in[0];
    const int*   ei = (const int*)d_in[1];     // [2, E]: row then col
    const float* w  = (const float*)d_in[2];
    const float* W1 = (const float*)d_in[3];
    const float* b1 = (const float*)d_in[4];
    const float* W2 = (const float*)d_in[5];
    const float* b2 = (const float*)d_in[6];
    float* out = (float*)d_out;

    const int* row = ei;
    const int* col = ei + N_EDGES;

    // workspace layout (64B-aligned offsets)
    char* ws = (char*)d_ws;
    int*      gcur  = (int*)(ws + 0);            //     3,200 B
    int2*     rp    = (int2*)(ws + 3200);        //   800,000 B
    float*    dinv  = (float*)(ws + 803200);     //   400,000 B
    unsigned* h1b   = (unsigned*)(ws + 1203200); // 3,200,000 B (bf16 16/row)
    float*    h2s   = (float*)(ws + 4403200);    //   800,000 B
    unsigned* ebuf4 = (unsigned*)(ws + 5203200); //14,814,208 B (782*4736*4)
    int2*     ebuf  = (int2*)(ws + 20017408);    //29,678,416 B (EBUF_SLOTS*8)
    // end: 49,695,824 B

    hipMemsetAsync(gcur, 0, 3200, stream);       // bucket counters = 0
    k_part    <<<NPBLK, 1024, 0, stream>>>(row, col, w, gcur, ebuf);
    k_sortxw1 <<<NBUCK, 1024, 0, stream>>>(gcur, ebuf, x, W1, ebuf4, rp, dinv, h1b);
    k_agg1    <<<(4 * N_NODES + 255) / 256, 256, 0, stream>>>(rp, ebuf4, (const uint4*)h1b, dinv, b1, W2, h2s);
    k_agg2    <<<(4 * N_NODES + 255) / 256, 256, 0, stream>>>(rp, ebuf4, h2s, dinv, b2, out);
}

// Round 14
// 189.699 us; speedup vs baseline: 7.3786x; 1.0492x over previous
//
#include <hip/hip_runtime.h>
#include <math.h>

#define N_NODES 100000
#define N_EDGES 3200000
#define F_IN    37
#define H_DIM   16
#define C_DIM   2

#define BUCKET_BITS 7
#define BUCKET_SZ   128
#define NBUCK       782          // ceil(100000/128)
#define CAP         4736         // bucket capacity: mean ~4092 + 10 sigma
#define NPBLK       512          // k_part grid (2 blocks/CU)
#define NCHUNK      512          // = NPBLK, chunks in ebuf
#define EB          6250         // edges per part block (512*6250 = 3.2M exactly)
#define EPT_P       7            // ceil(6250/1024)
#define EPT_S       5            // ceil(CAP/1024)

__device__ __forceinline__ unsigned bf16rne(float f) {
    unsigned u = __float_as_uint(f);
    return (u + 0x7FFFu + ((u >> 16) & 1u)) >> 16;
}
__device__ __forceinline__ int2 ldnt_i2(const int2* p) {
    long long v = __builtin_nontemporal_load((const long long*)p);
    return *(int2*)&v;
}
#define BLO(u) __uint_as_float((u) << 16)
#define BHI(u) __uint_as_float((u) & 0xFFFF0000u)
// compact edge decode: u = (w_bf16 << 17) | row   (w in [0,1) => sign bit 0)
#define EW(u)  __uint_as_float(((u) >> 17) << 16)
#define ER(u)  ((u) & 0x1FFFFu)

// ---------- partition, TRANSPOSED OUTPUT: bucket-sort within chunk, write the
// chunk CONTIGUOUSLY (pure 50KB stream, full lines) + per-bucket segment
// starts to bases[]. Deletes: gcur atomics, page-table walk, scattered 64B
// writes (R12 insight: 400K partial-line write granules), and the memset
// dispatch (offsets now deterministic). ----------
__global__ __launch_bounds__(1024) void k_part(
    const int* __restrict__ row, const int* __restrict__ col,
    const float* __restrict__ w, int* __restrict__ bases, int2* __restrict__ ebuf)
{
    __shared__ int  cnt[NBUCK];
    __shared__ int  base[NBUCK];               // inclusive scan
    __shared__ int  wscan[16];                 // per-wave scan sums
    __shared__ int2 stage[EB];                 // 50 KB
    int t = threadIdx.x;
    size_t e0 = (size_t)blockIdx.x * EB;
    int bk[EPT_P], rc[EPT_P], lofs[EPT_P];
    float wv[EPT_P];

    if (t < NBUCK) cnt[t] = 0;
    __syncthreads();
#pragma unroll
    for (int k = 0; k < EPT_P; k++) {
        int i = k * 1024 + t;
        if (i < EB) {
            size_t e = e0 + i;
            int r = __builtin_nontemporal_load(&row[e]);
            int c = __builtin_nontemporal_load(&col[e]);
            wv[k] = __builtin_nontemporal_load(&w[e]);
            bk[k] = (c >> BUCKET_BITS) & 1023;         // clamp-mask (c<2^17 anyway)
            if (bk[k] >= NBUCK) bk[k] = NBUCK - 1;     // unreachable guard
            rc[k] = (r & 0x1FFFF) | ((c & (BUCKET_SZ - 1)) << 17);
            lofs[k] = atomicAdd(&cnt[bk[k]], 1);
        } else bk[k] = -1;
    }
    __syncthreads();
    // ---- inclusive scan of cnt[782]: per-wave shfl scan + cross-wave ----
    {
        int lane = t & 63, wid = t >> 6;
        int v = (t < NBUCK) ? cnt[t] : 0;
#pragma unroll
        for (int d = 1; d < 64; d <<= 1) {
            int u = __shfl_up(v, d);
            if (lane >= d) v += u;
        }
        if (lane == 63) wscan[wid] = v;
        __syncthreads();
        if (wid == 0) {
            int u = (lane < 16) ? wscan[lane] : 0;
#pragma unroll
            for (int d = 1; d < 16; d <<= 1) {
                int u2 = __shfl_up(u, d);
                if (lane >= d) u += u2;
            }
            if (lane < 16) wscan[lane] = u;    // inclusive scan of wave sums
        }
        __syncthreads();
        if (t < NBUCK) base[t] = v + ((wid > 0) ? wscan[wid - 1] : 0);
    }
    __syncthreads();
    // scatter into LDS stage, bucket-sorted within this chunk
#pragma unroll
    for (int k = 0; k < EPT_P; k++) {
        if (bk[k] >= 0) {
            int pos = base[bk[k]] - cnt[bk[k]] + lofs[k];
            if (pos >= 0 && pos < EB) stage[pos] =     // unreachable guard
                make_int2(rc[k], __float_as_int(wv[k]));
        }
    }
    // publish per-bucket exclusive starts (start[b+1] implicit = start via b+1)
    if (t < NBUCK) bases[blockIdx.x * NBUCK + t] = base[t] - cnt[t];
    __syncthreads();
    // linear write-out: contiguous 50KB stream, full lines
    {
        size_t o = (size_t)blockIdx.x * EB;
        for (int s2 = t; s2 < EB; s2 += 1024)
            ebuf[o + s2] = stage[s2];
    }
}

// ---------- fused: gather bucket's 512 chunk-segments -> per-bucket LDS
// counting sort -> compact 4B edges + CSR + dinv + h1b. Sort body, deg,
// ebuf4 write, xw1 are R7-VERBATIM (proven 191.0us); only the load source
// changed (contiguous global stream -> 512-segment gather). ----------
__global__ __launch_bounds__(1024) void k_sortxw1(
    const int* __restrict__ bases, const int2* __restrict__ ebuf,
    const float* __restrict__ x, const float* __restrict__ W1,
    unsigned* __restrict__ ebuf4, int2* __restrict__ rp,
    float* __restrict__ dinv, unsigned* __restrict__ h1b)
{
    __shared__ int2  stage[CAP];              // 37.9 KB (reused as xs below)
    __shared__ int   cnt[BUCKET_SZ];
    __shared__ int   base[BUCKET_SZ];
    __shared__ float sdinv[BUCKET_SZ];
    __shared__ int   wscan[16];
    __shared__ float sW[F_IN * H_DIM];        // 2.4 KB
    __shared__ int   cstart[NCHUNK];          // segment start within chunk
    __shared__ int   ccount[NCHUNK];          // segment length
    __shared__ int   cbase[NCHUNK];           // exclusive base in stage
    __shared__ int   slen;
    float* xs = (float*)stage;                // aliased reuse: 128*37 floats

    int t = threadIdx.x, bid = blockIdx.x;
    // XCD-contiguous bucket mapping: adjacent buckets (which share gather
    // cache lines) land on the same XCD's L2. Bijective: xcd<6 -> 98 each,
    // xcd 6,7 -> 97 each (782 = 6*98 + 2*97).
    int xcd = bid & 7, ii = bid >> 3;
    int b = (xcd < 6) ? xcd * 98 + ii : 588 + (xcd - 6) * 97 + ii;
    int s = b * CAP;
    int nbase = b << BUCKET_BITS;
    if (t < BUCKET_SZ) cnt[t] = 0;

    // ---- per-chunk segment table + 512-entry scan ----
    int myc = 0, vincl = 0;
    if (t < NCHUNK) {
        int st = bases[t * NBUCK + b];
        int en = (b == NBUCK - 1) ? EB : bases[t * NBUCK + b + 1];
        if (st < 0) st = 0; if (st > EB) st = EB;      // unreachable guards
        if (en < st) en = st; if (en > EB) en = EB;
        myc = en - st;
        if (myc > 64) myc = 64;                        // unreachable guard
        cstart[t] = st;
        ccount[t] = myc;
    }
    {
        int lane = t & 63;
        vincl = myc;
#pragma unroll
        for (int d = 1; d < 64; d <<= 1) {
            int u = __shfl_up(vincl, d);
            if (lane >= d) vincl += u;
        }
        if (t < NCHUNK && lane == 63) wscan[t >> 6] = vincl;
    }
    __syncthreads();
    if (t < 64) {                                      // cross-wave scan (8 sums)
        int u = (t < 8) ? wscan[t] : 0;
#pragma unroll
        for (int d = 1; d < 8; d <<= 1) {
            int u2 = __shfl_up(u, d);
            if (t >= d) u += u2;
        }
        if (t < 8) wscan[t] = u;
    }
    __syncthreads();
    if (t < NCHUNK) {
        int wid = t >> 6;
        int incl = vincl + ((wid > 0) ? wscan[wid - 1] : 0);
        cbase[t] = incl - myc;
        if (t == NCHUNK - 1) slen = incl;
    }
    __syncthreads();
    int len = slen;
    if (len > CAP) len = CAP;                          // unreachable guard

    // ---- gather: 2 threads/chunk copy its ~8-edge segment into stage ----
    {
        int p = t >> 1, h = t & 1;
        int st = cstart[p], cb = cbase[p], cc = ccount[p];
        const int2* src = &ebuf[(size_t)p * EB + st];
        for (int i = h; i < cc; i += 2) {
            int pos = cb + i;
            if (pos >= 0 && pos < CAP) stage[pos] = src[i];
        }
    }
    __syncthreads();

    // ---- load + count (from LDS; R7-verbatim otherwise) ----
    int2 ed[EPT_S]; int cl[EPT_S], lofs[EPT_S];
#pragma unroll
    for (int k = 0; k < EPT_S; k++) {
        int i = k * 1024 + t;
        if (i < len) {
            int2 v = stage[i];
            ed[k] = v;
            cl[k] = (v.x >> 17) & (BUCKET_SZ - 1);
            lofs[k] = atomicAdd(&cnt[cl[k]], 1);
        } else cl[k] = -1;
    }
    __syncthreads();
    // ---- inclusive scan of cnt[128]: per-wave shfl scan + cross-wave ----
    {
        int lane = t & 63, wid = t >> 6;
        int v = (t < BUCKET_SZ) ? cnt[t] : 0;
#pragma unroll
        for (int d = 1; d < 64; d <<= 1) {
            int u = __shfl_up(v, d);
            if (lane >= d) v += u;
        }
        if (lane == 63) wscan[wid] = v;
        __syncthreads();
        if (wid == 0) {
            int u = (lane < 16) ? wscan[lane] : 0;
#pragma unroll
            for (int d = 1; d < 16; d <<= 1) {
                int u2 = __shfl_up(u, d);
                if (lane >= d) u += u2;
            }
            if (lane < 16) wscan[lane] = u;
        }
        __syncthreads();
        if (t < BUCKET_SZ) base[t] = v + ((wid > 0) ? wscan[wid - 1] : 0);
    }
    __syncthreads();
    // ---- scatter into LDS stage in node-sorted order ----
#pragma unroll
    for (int k = 0; k < EPT_S; k++) {
        if (cl[k] >= 0) {
            int pos = base[cl[k]] - cnt[cl[k]] + lofs[k];
            if (pos >= 0 && pos < CAP) stage[pos] = ed[k];   // unreachable guard
        }
    }
    __syncthreads();
    // ---- compact 4B write-back (NT, coalesced => full-line writes) ----
    for (int i = t; i < len; i += 1024) {
        int2 v = stage[i];
        unsigned wb = bf16rne(__int_as_float(v.y));
        __builtin_nontemporal_store((wb << 17) | (unsigned)(v.x & 0x1FFFF),
                                    &ebuf4[s + i]);
    }
    // ---- degree -> dinv: 8 threads/node strided + shfl reduce ----
    {
        int n = t >> 3, l = t & 7;
        int st = base[n] - cnt[n], cn = cnt[n];
        float sum = 0.f;
        for (int i = l; i < cn; i += 8) sum += __int_as_float(stage[st + i].y);
        sum += __shfl_xor(sum, 1);
        sum += __shfl_xor(sum, 2);
        sum += __shfl_xor(sum, 4);
        if (l == 0) {
            float di = rsqrtf(sum + 1.0f);    // + self-loop
            sdinv[n] = di;
            int c = nbase + n;
            if (c < N_NODES) {
                rp[c] = make_int2(s + st, cn);
                dinv[c] = di;
            }
        }
    }
    __syncthreads();                          // stage reads done; xs overwrite ok

    // ---- fused xw1 for this bucket's 128 nodes ----
    for (int idx = t; idx < F_IN * H_DIM; idx += 1024) sW[idx] = W1[idx];
    {
        const float4* x4 = (const float4*)(x + (size_t)nbase * F_IN);
        const int nv4 = (BUCKET_SZ * F_IN) / 4;   // 1184
        int gf0 = nbase * F_IN;
        for (int idx = t; idx < nv4; idx += 1024) {
            int gf = gf0 + 4 * idx;
            float4 v;
            if (gf + 3 < N_NODES * F_IN) {
                v = x4[idx];
            } else {
                v.x = (gf + 0 < N_NODES * F_IN) ? x[gf + 0] : 0.f;
                v.y = (gf + 1 < N_NODES * F_IN) ? x[gf + 1] : 0.f;
                v.z = (gf + 2 < N_NODES * F_IN) ? x[gf + 2] : 0.f;
                v.w = (gf + 3 < N_NODES * F_IN) ? x[gf + 3] : 0.f;
            }
            ((float4*)xs)[idx] = v;
        }
    }
    __syncthreads();
    // 8 threads/node, each computes 2 output cols {2*sub, 2*sub+1}
    {
        int n = t >> 3, sub = t & 7;
        int c = nbase + n;
        if (c < N_NODES) {
            const float* xi = &xs[n * F_IN];
            float a0 = 0.f, a1 = 0.f;
            for (int k = 0; k < F_IN; k++) {
                float xv = xi[k];
                a0 += xv * sW[k * H_DIM + 2 * sub];
                a1 += xv * sW[k * H_DIM + 2 * sub + 1];
            }
            float di = sdinv[n];
            unsigned pk = bf16rne(di * a0) | (bf16rne(di * a1) << 16);
            h1b[(size_t)c * 8 + sub] = pk;    // 32B/node, coalesced
        }
    }
}

// ---------- layer 1: 8 lanes/node (R7-verbatim, proven 191.0; R12 proved
// 4-lane regresses, 16/8 equal => TLP-saturated flat optimum) ----------
__global__ __launch_bounds__(256) void k_agg1(
    const int2* __restrict__ rp, const unsigned* __restrict__ ebuf4,
    const uint4* __restrict__ h1b, const float* __restrict__ dinv,
    const float* __restrict__ b1, const float* __restrict__ W2,
    float* __restrict__ h2s)
{
    __shared__ float sW2[H_DIM * C_DIM];
    __shared__ float sb1[H_DIM];
    int t = threadIdx.x;
    if (t < H_DIM * C_DIM) sW2[t] = W2[t];
    if (t >= 32 && t < 32 + H_DIM) sb1[t - 32] = b1[t - 32];
    __syncthreads();
    int id = blockIdx.x * 256 + t;
    int c = id >> 3;                           // 8 lanes per node
    int sub = id & 7;
    if (c >= N_NODES) return;
    int2 seg = rp[c];
    int s = seg.x, n = seg.y;
    int m = (n - sub + 7) >> 3;                // edges for this eighth (stride 8)
    int p0i = s + sub;
    float acc[16];
#pragma unroll
    for (int j = 0; j < 16; j++) acc[j] = 0.f;

#define PROC1(u)                                                    \
    {   float a = EW(u);                                            \
        size_t rr = (size_t)ER(u) * 2;                              \
        uint4 g0 = h1b[rr];                                         \
        uint4 g1 = h1b[rr + 1];                                     \
        acc[0]  += a * BLO(g0.x); acc[1]  += a * BHI(g0.x);         \
        acc[2]  += a * BLO(g0.y); acc[3]  += a * BHI(g0.y);         \
        acc[4]  += a * BLO(g0.z); acc[5]  += a * BHI(g0.z);         \
        acc[6]  += a * BLO(g0.w); acc[7]  += a * BHI(g0.w);         \
        acc[8]  += a * BLO(g1.x); acc[9]  += a * BHI(g1.x);         \
        acc[10] += a * BLO(g1.y); acc[11] += a * BHI(g1.y);         \
        acc[12] += a * BLO(g1.z); acc[13] += a * BHI(g1.z);         \
        acc[14] += a * BLO(g1.w); acc[15] += a * BHI(g1.w); }

    int k = 0;
    if (m >= 4) {
        unsigned e0 = __builtin_nontemporal_load(&ebuf4[p0i + 0]);
        unsigned e1 = __builtin_nontemporal_load(&ebuf4[p0i + 8]);
        unsigned e2 = __builtin_nontemporal_load(&ebuf4[p0i + 16]);
        unsigned e3 = __builtin_nontemporal_load(&ebuf4[p0i + 24]);
        for (; k + 8 <= m; k += 4) {
            unsigned f0 = __builtin_nontemporal_load(&ebuf4[p0i + 8 * (k + 4)]);
            unsigned f1 = __builtin_nontemporal_load(&ebuf4[p0i + 8 * (k + 5)]);
            unsigned f2 = __builtin_nontemporal_load(&ebuf4[p0i + 8 * (k + 6)]);
            unsigned f3 = __builtin_nontemporal_load(&ebuf4[p0i + 8 * (k + 7)]);
            PROC1(e0); PROC1(e1); PROC1(e2); PROC1(e3);
            e0 = f0; e1 = f1; e2 = f2; e3 = f3;
        }
        PROC1(e0); PROC1(e1); PROC1(e2); PROC1(e3);
        k += 4;
    }
    for (; k < m; k++) {
        unsigned u = __builtin_nontemporal_load(&ebuf4[p0i + 8 * k]);
        PROC1(u);
    }
#undef PROC1

    // combine the 8 segment-eighths
#pragma unroll
    for (int j = 0; j < 16; j++) {
        acc[j] += __shfl_xor(acc[j], 1);
        acc[j] += __shfl_xor(acc[j], 2);
        acc[j] += __shfl_xor(acc[j], 4);
    }

    // epilogue: each lane finishes 2 features {2*sub, 2*sub+1}
    float dc = dinv[c];
    const unsigned* h1w = (const unsigned*)h1b;
    unsigned gs = h1w[(size_t)c * 8 + sub];    // self term, 2 bf16 features
    float r0 = fmaxf(dc * (acc[2 * sub]     + BLO(gs)) + sb1[2 * sub],     0.f);
    float r1 = fmaxf(dc * (acc[2 * sub + 1] + BHI(gs)) + sb1[2 * sub + 1], 0.f);
    float p0 = r0 * sW2[(2 * sub) * C_DIM + 0] + r1 * sW2[(2 * sub + 1) * C_DIM + 0];
    float p1 = r0 * sW2[(2 * sub) * C_DIM + 1] + r1 * sW2[(2 * sub + 1) * C_DIM + 1];
    p0 += __shfl_xor(p0, 1); p0 += __shfl_xor(p0, 2); p0 += __shfl_xor(p0, 4);
    p1 += __shfl_xor(p1, 1); p1 += __shfl_xor(p1, 2); p1 += __shfl_xor(p1, 4);
    if (sub == 0) ((float2*)h2s)[c] = make_float2(dc * p0, dc * p1);
}

// ---------- layer 2: 8 lanes/node (R7-verbatim, proven) ----------
__global__ __launch_bounds__(256) void k_agg2(
    const int2* __restrict__ rp, const unsigned* __restrict__ ebuf4,
    const float* __restrict__ h2s, const float* __restrict__ dinv,
    const float* __restrict__ b2, float* __restrict__ out)
{
    int id = blockIdx.x * 256 + threadIdx.x;
    int c = id >> 3, sub = id & 7;
    if (c >= N_NODES) return;
    int2 seg = rp[c];
    int s = seg.x, n = seg.y;
    const float2* h22 = (const float2*)h2s;
    int m = (n - sub + 7) >> 3;                // edges for this eighth (stride 8)
    int p0i = s + sub;
    float a0 = 0.f, a1 = 0.f;

#define PROC2(u)                                                    \
    {   float a = EW(u);                                            \
        float2 hv = h22[ER(u)];                                     \
        a0 += a * hv.x;  a1 += a * hv.y; }

    int k = 0;
    if (m >= 4) {
        unsigned e0 = __builtin_nontemporal_load(&ebuf4[p0i + 0]);
        unsigned e1 = __builtin_nontemporal_load(&ebuf4[p0i + 8]);
        unsigned e2 = __builtin_nontemporal_load(&ebuf4[p0i + 16]);
        unsigned e3 = __builtin_nontemporal_load(&ebuf4[p0i + 24]);
        for (; k + 8 <= m; k += 4) {
            unsigned f0 = __builtin_nontemporal_load(&ebuf4[p0i + 8 * (k + 4)]);
            unsigned f1 = __builtin_nontemporal_load(&ebuf4[p0i + 8 * (k + 5)]);
            unsigned f2 = __builtin_nontemporal_load(&ebuf4[p0i + 8 * (k + 6)]);
            unsigned f3 = __builtin_nontemporal_load(&ebuf4[p0i + 8 * (k + 7)]);
            PROC2(e0); PROC2(e1); PROC2(e2); PROC2(e3);
            e0 = f0; e1 = f1; e2 = f2; e3 = f3;
        }
        PROC2(e0); PROC2(e1); PROC2(e2); PROC2(e3);
        k += 4;
    }
    for (; k < m; k++) {
        unsigned u = __builtin_nontemporal_load(&ebuf4[p0i + 8 * k]);
        PROC2(u);
    }
#undef PROC2

    a0 += __shfl_xor(a0, 1); a0 += __shfl_xor(a0, 2); a0 += __shfl_xor(a0, 4);
    a1 += __shfl_xor(a1, 1); a1 += __shfl_xor(a1, 2); a1 += __shfl_xor(a1, 4);
    if (sub == 0) {
        float dc = dinv[c];
        float2 hc = h22[c];
        float l0 = dc * (a0 + hc.x) + b2[0];
        float l1 = dc * (a1 + hc.y) + b2[1];
        float mx = fmaxf(l0, l1);
        float lse = mx + logf(expf(l0 - mx) + expf(l1 - mx));
        ((float2*)out)[c] = make_float2(l0 - lse, l1 - lse);
    }
}

extern "C" void kernel_launch(void* const* d_in, const int* in_sizes, int n_in,
                              void* d_out, int out_size, void* d_ws, size_t ws_size,
                              hipStream_t stream) {
    const float* x  = (const float*)d_in[0];
    const int*   ei = (const int*)d_in[1];     // [2, E]: row then col
    const float* w  = (const float*)d_in[2];
    const float* W1 = (const float*)d_in[3];
    const float* b1 = (const float*)d_in[4];
    const float* W2 = (const float*)d_in[5];
    const float* b2 = (const float*)d_in[6];
    float* out = (float*)d_out;

    const int* row = ei;
    const int* col = ei + N_EDGES;

    // workspace layout (64B-aligned offsets). NOTE: no memset needed —
    // bases[] is fully rewritten by k_part every launch (deterministic).
    char* ws = (char*)d_ws;
    int*      bases = (int*)(ws + 0);            // 1,600,768 B (512*782*4)
    int2*     rp    = (int2*)(ws + 1600768);     //   800,000 B
    float*    dinv  = (float*)(ws + 2400768);    //   400,000 B
    unsigned* h1b   = (unsigned*)(ws + 2800768); // 3,200,000 B (bf16 16/row)
    float*    h2s   = (float*)(ws + 6000768);    //   800,000 B
    unsigned* ebuf4 = (unsigned*)(ws + 6800768); //14,814,208 B (782*4736*4)
    int2*     ebuf  = (int2*)(ws + 21614976);    //25,600,000 B (512*6250*8)
    // end: 47,214,976 B

    k_part    <<<NPBLK, 1024, 0, stream>>>(row, col, w, bases, ebuf);
    k_sortxw1 <<<NBUCK, 1024, 0, stream>>>(bases, ebuf, x, W1, ebuf4, rp, dinv, h1b);
    k_agg1    <<<(8 * N_NODES + 255) / 256, 256, 0, stream>>>(rp, ebuf4, (const uint4*)h1b, dinv, b1, W2, h2s);
    k_agg2    <<<(8 * N_NODES + 255) / 256, 256, 0, stream>>>(rp, ebuf4, h2s, dinv, b2, out);
}